// Round 17
// baseline (565.750 us; speedup 1.0000x reference)
//
#include <hip/hip_runtime.h>

typedef __attribute__((ext_vector_type(8))) short bf16x8;
typedef __attribute__((ext_vector_type(4))) short bf16x4;
typedef __attribute__((ext_vector_type(4))) float f32x4;
typedef __attribute__((ext_vector_type(2))) unsigned u32x2;

#define MFMA16(a, b, c) __builtin_amdgcn_mfma_f32_16x16x32_bf16(a, b, c, 0, 0, 0)

static __device__ __forceinline__ short f2bf(float f) {
    union { float f; unsigned u; } x; x.f = f;
    unsigned r = x.u + 0x7FFFu + ((x.u >> 16) & 1u);
    return (short)(r >> 16);
}

static __device__ __forceinline__ unsigned cvtpk(float lo, float hi) {
    unsigned r;
    asm("v_cvt_pk_bf16_f32 %0, %1, %2" : "=v"(r) : "v"(lo), "v"(hi));
    return r;
}

static __device__ __forceinline__ void gload16(const void* g, void* l) {
    __builtin_amdgcn_global_load_lds((const __attribute__((address_space(1))) void*)g,
                                     (__attribute__((address_space(3))) void*)l, 16, 0, 0);
}

static __device__ __forceinline__ float gelu(float t) {
    return 0.5f * t * (1.f + erff(t * 0.70710678118f));
}

// ---------- all 4 weight transposes for one layer in one launch ----------
__global__ void wconv_kernel(const float* __restrict__ i_qkv, const float* __restrict__ i_o,
                             const float* __restrict__ i_m1, const float* __restrict__ i_m2,
                             short* __restrict__ wqkv, short* __restrict__ wo,
                             short* __restrict__ wm1, short* __restrict__ wm2) {
    int idx = blockIdx.x * 256 + threadIdx.x;
    if (idx < 196608) {                       // qkv: (128,1536) -> (1536,128)
        int k = idx & 127, n = idx >> 7;
        wqkv[idx] = f2bf(i_qkv[k * 1536 + n]);
    } else if (idx < 262144) {                // w_o: (512,128) -> (128,512)
        int l = idx - 196608; int k = l & 511, n = l >> 9;
        wo[l] = f2bf(i_o[k * 128 + n]);
    } else if (idx < 327680) {                // w_m1: (128,512) -> (512,128)
        int l = idx - 262144; int k = l & 127, n = l >> 7;
        wm1[l] = f2bf(i_m1[k * 512 + n]);
    } else {                                  // w_m2: (512,128) -> (128,512)
        int l = idx - 327680; int k = l & 511, n = l >> 9;
        wm2[l] = f2bf(i_m2[k * 128 + n]);
    }
}

// ---------- MT[h][e][d] = SC * sum_o Wq[d,o]*Wk[e,o]  (dots = X M X^T) ----------
__global__ __launch_bounds__(128) void mtgen_kernel(const float* __restrict__ wqkv,
                                                    short* __restrict__ mt) {
    const int h = blockIdx.x >> 7, e = blockIdx.x & 127;
    __shared__ float s_wk[128];
    const int d = threadIdx.x;
    s_wk[d] = wqkv[(size_t)e * 1536 + 512 + h * 128 + d];
    __syncthreads();
    const float* wq = wqkv + (size_t)d * 1536 + h * 128;
    float acc = 0.f;
#pragma unroll
    for (int o = 0; o < 128; ++o) acc += wq[o] * s_wk[o];
    mt[(size_t)(h * 128 + e) * 128 + d] = f2bf(acc * 0.08838834764831845f);
}

// ---------- bias+mask table: tab[5][64][64] ----------
__global__ void tabgen_kernel(const float* __restrict__ pos_a, const float* __restrict__ pos_b,
                              float* __restrict__ tab) {
    int v = blockIdx.x;
    const float* pos = (v == 0) ? pos_a : pos_b;
    for (int e = threadIdx.x; e < 4096; e += 256) {
        int row = e >> 6, key = e & 63;
        float val;
        if (key >= 49) val = -1e9f;
        else if (row >= 49) val = 0.f;
        else {
            int qi = row / 7, qj = row - qi * 7, ki = key / 7, kj = key - ki * 7;
            val = pos[(ki - qi + 6) * 13 + (kj - qj + 6)];
            if (v >= 1) {
                bool wh7 = (v - 1) & 2, ww7 = (v - 1) & 1;
                if (wh7 && ((qi >= 4) != (ki >= 4))) val += -1e9f;
                if (ww7 && ((qj >= 4) != (kj >= 4))) val += -1e9f;
            }
        }
        tab[v * 4096 + e] = val;
    }
}

// ---------- patch embed + LN1a: out f32 + xn bf16 ----------
__global__ __launch_bounds__(256) void patchln_kernel(const float* __restrict__ x,
                                                      const float* __restrict__ w,
                                                      const float* __restrict__ bias,
                                                      const float* __restrict__ g,
                                                      const float* __restrict__ bta,
                                                      float* __restrict__ out,
                                                      short* __restrict__ xn) {
    __shared__ float s_in[2][48];
    __shared__ float red[2][2][2];
    const int tid = threadIdx.x;
    const int half = tid >> 7, c = tid & 127;
    const int winh = (tid >> 6) & 1, lane = tid & 63;
    const int t = blockIdx.x * 2 + half;
    const int b = t / 3136, rem = t - b * 3136;
    const int hp = rem / 56, wp = rem - hp * 56;
    if (c < 48) {
        int cin = c >> 4, py = (c >> 2) & 3, px = c & 3;
        s_in[half][c] = x[((size_t)(b * 3 + cin) * 224 + hp * 4 + py) * 224 + wp * 4 + px];
    }
    __syncthreads();
    float acc = bias[c];
#pragma unroll
    for (int k = 0; k < 48; ++k) acc += s_in[half][k] * w[k * 128 + c];
    out[(size_t)t * 128 + c] = acc;
    float s1 = acc, s2 = acc * acc;
#pragma unroll
    for (int o = 32; o > 0; o >>= 1) { s1 += __shfl_xor(s1, o); s2 += __shfl_xor(s2, o); }
    if (lane == 0) { red[half][winh][0] = s1; red[half][winh][1] = s2; }
    __syncthreads();
    s1 = red[half][0][0] + red[half][1][0];
    s2 = red[half][0][1] + red[half][1][1];
    float mean = s1 * (1.f / 128.f);
    float var = s2 * (1.f / 128.f) - mean * mean;
    float rstd = rsqrtf(var + 1e-5f);
    xn[(size_t)t * 128 + c] = f2bf((acc - mean) * rstd * g[c] + bta[c]);
}

// ---------- fused window attention v17: r12 skeleton + PV^T epilogue ----------
template <int SHIFTED>
__global__ __launch_bounds__(256, 3) void attn_kernel(const short* __restrict__ xn,
                                                      const short* __restrict__ wqkvT,
                                                      const short* __restrict__ mt,
                                                      const float* __restrict__ tab,
                                                      const short* __restrict__ zpad,
                                                      short* __restrict__ aout) {
    __shared__ short smem[24576];               // 48 KB
    short* s_x = smem;                          // X: 64 x 256B (swizzled); after bar3: P 64 x 128B
    short* s_T = smem + 8192;                   // T = X@M: 64 x 256B
    short* s_v = smem + 16384;                  // V^T: 128 x 128B
    short* s_p = smem;                          // P overlays s_x after bar3

    const int tid = threadIdx.x;
    const int wid = tid >> 6, lane = tid & 63;
    const int l15 = lane & 15, l4 = lane >> 4, klo = l4 * 8;
    const int bid = blockIdx.x;
    // win-fastest: the 4 heads of a window sit 64 apart -> same XCD (L2 locality)
    const int win = bid & 63, head = (bid >> 6) & 3, b = bid >> 8;
    const int wh = win >> 3, ww = win & 7;

    // token index for rows j*16+l15 (clamped at 48; only used for rows < 49)
    int trow[4];
#pragma unroll
    for (int j = 0; j < 4; ++j) {
        int r = j * 16 + l15; r = (r > 48) ? 48 : r;
        int wi = (r * 37) >> 8, wj = r - wi * 7;
        int hh = wh * 7 + wi, wp = ww * 7 + wj;
        if (SHIFTED) { hh += 3; if (hh >= 56) hh -= 56; wp += 3; if (wp >= 56) wp -= 56; }
        trow[j] = (b * 56 + hh) * 56 + wp;
    }

    // ---- stage X window into swizzled s_x via global_load_lds ----
#pragma unroll
    for (int it = 0; it < 4; ++it) {
        int slot = it * 256 + tid;
        int row = slot >> 4, scol = slot & 15;
        int colb = (scol * 16) ^ ((row & 7) << 4);
        const char* g;
        if (row < 49) {
            int wi = (row * 37) >> 8, wj = row - wi * 7;
            int hh = wh * 7 + wi, wp = ww * 7 + wj;
            if (SHIFTED) { hh += 3; if (hh >= 56) hh -= 56; wp += 3; if (wp >= 56) wp -= 56; }
            int t = (b * 56 + hh) * 56 + wp;
            g = (const char*)(xn + (size_t)t * 128) + colb;
        } else {
            g = (const char*)zpad + colb;
        }
        gload16(g, (char*)smem + (it * 256 + wid * 64) * 16);
    }
    __syncthreads();   // bar1

    const f32x4 zero4 = {0.f, 0.f, 0.f, 0.f};

    // ---- merged T = X@M  and  V = X@Wv (shared X fragments) ----
    {
        const short* Mh = mt + (size_t)head * 16384;
        const short* Wv = wqkvT + (size_t)(1024 + head * 128) * 128;
        f32x4 at[2][4], av[4][2];
#pragma unroll
        for (int mw = 0; mw < 2; ++mw)
#pragma unroll
            for (int j = 0; j < 4; ++j) at[mw][j] = zero4;
#pragma unroll
        for (int m = 0; m < 4; ++m)
#pragma unroll
            for (int n = 0; n < 2; ++n) av[m][n] = zero4;
#pragma unroll
        for (int k0 = 0; k0 < 4; ++k0) {
            bf16x8 bx[4], awt[2], bwv[2];
#pragma unroll
            for (int j = 0; j < 4; ++j) {
                int row = j * 16 + l15;
                bx[j] = *(const bf16x8*)((const char*)s_x + row * 256 + ((k0 * 64 + l4 * 16) ^ ((row & 7) << 4)));
            }
#pragma unroll
            for (int mw = 0; mw < 2; ++mw)
                awt[mw] = *(const bf16x8*)(Mh + (size_t)(wid * 32 + mw * 16 + l15) * 128 + k0 * 32 + klo);
#pragma unroll
            for (int n = 0; n < 2; ++n)
                bwv[n] = *(const bf16x8*)(Wv + (size_t)(wid * 32 + n * 16 + l15) * 128 + k0 * 32 + klo);
            __builtin_amdgcn_s_setprio(1);
#pragma unroll
            for (int mw = 0; mw < 2; ++mw)
#pragma unroll
                for (int j = 0; j < 4; ++j) at[mw][j] = MFMA16(awt[mw], bx[j], at[mw][j]);
#pragma unroll
            for (int m = 0; m < 4; ++m)
#pragma unroll
                for (int n = 0; n < 2; ++n) av[m][n] = MFMA16(bx[m], bwv[n], av[m][n]);
            __builtin_amdgcn_s_setprio(0);
        }
        // T store (token-major 256B rows)
#pragma unroll
        for (int mw = 0; mw < 2; ++mw)
#pragma unroll
            for (int j = 0; j < 4; ++j) {
                u32x2 pq = { cvtpk(at[mw][j][0], at[mw][j][1]), cvtpk(at[mw][j][2], at[mw][j][3]) };
                int row = j * 16 + l15;
                *(u32x2*)((char*)s_T + row * 256 + ((wid * 64 + mw * 32 + l4 * 8) ^ ((row & 7) << 4))) = pq;
            }
        // V^T store (head-dim-major 128B rows)
#pragma unroll
        for (int m = 0; m < 4; ++m)
#pragma unroll
            for (int n = 0; n < 2; ++n) {
                u32x2 pv = { cvtpk(av[m][n][0], av[m][n][1]), cvtpk(av[m][n][2], av[m][n][3]) };
                int hd = wid * 32 + n * 16 + l15;
                *(u32x2*)((char*)s_v + hd * 128 + ((m * 32 + l4 * 8) ^ ((hd & 7) << 4))) = pv;
            }
    }
    __syncthreads();   // bar2: T and V visible

    // ---- dots^T = mfma(X, T): lane holds query-row qrow's 16 scores ----
    const int qrow = wid * 16 + l15;
    f32x4 dt[4];
#pragma unroll
    for (int m = 0; m < 4; ++m) dt[m] = zero4;
#pragma unroll
    for (int k0 = 0; k0 < 4; ++k0) {
        bf16x8 bq = *(const bf16x8*)((const char*)s_T + qrow * 256 + ((k0 * 64 + l4 * 16) ^ ((qrow & 7) << 4)));
        __builtin_amdgcn_s_setprio(1);
#pragma unroll
        for (int m = 0; m < 4; ++m) {
            int krow = m * 16 + l15;
            bf16x8 akf = *(const bf16x8*)((const char*)s_x + krow * 256 + ((k0 * 64 + l4 * 16) ^ ((krow & 7) << 4)));
            dt[m] = MFMA16(akf, bq, dt[m]);
        }
        __builtin_amdgcn_s_setprio(0);
    }
    __syncthreads();   // bar3: ALL waves done reading s_x -> region dead, safe for P

    // ---- in-register softmax (SC folded into M); P -> dead s_x region ----
    const int variant = SHIFTED ? (1 + ((wh == 7) ? 2 : 0) + ((ww == 7) ? 1 : 0)) : 0;
    const float* tv = tab + variant * 4096 + qrow * 64;
    float p[4][4];
    float mx = -3.0e38f;
#pragma unroll
    for (int m = 0; m < 4; ++m) {
        f32x4 tb = *(const f32x4*)(tv + m * 16 + l4 * 4);
#pragma unroll
        for (int r = 0; r < 4; ++r) {
            float d = dt[m][r] + tb[r];
            p[m][r] = d;
            mx = fmaxf(mx, d);
        }
    }
    mx = fmaxf(mx, __shfl_xor(mx, 16));
    mx = fmaxf(mx, __shfl_xor(mx, 32));
    float sum = 0.f;
#pragma unroll
    for (int m = 0; m < 4; ++m)
#pragma unroll
        for (int r = 0; r < 4; ++r) { p[m][r] = __expf(p[m][r] - mx); sum += p[m][r]; }
    sum += __shfl_xor(sum, 16);
    sum += __shfl_xor(sum, 32);
    float inv = 1.f / sum;
#pragma unroll
    for (int m = 0; m < 4; ++m) {
        u32x2 pv = { cvtpk(p[m][0] * inv, p[m][1] * inv), cvtpk(p[m][2] * inv, p[m][3] * inv) };
        *(u32x2*)((char*)s_p + qrow * 128 + ((m * 32 + l4 * 8) ^ ((qrow & 7) << 4))) = pv;
    }
    __syncthreads();   // bar4: P visible to all waves

    // ---- out^T = mfma(V^T, P): lane gets 4 consecutive features of one token ----
    f32x4 o[2][4];
#pragma unroll
    for (int fn = 0; fn < 2; ++fn)
#pragma unroll
        for (int tm = 0; tm < 4; ++tm) o[fn][tm] = zero4;
#pragma unroll
    for (int k0 = 0; k0 < 2; ++k0) {
        bf16x8 ap[4], bv2[2];
#pragma unroll
        for (int tm = 0; tm < 4; ++tm) {
            int row = tm * 16 + l15;
            ap[tm] = *(const bf16x8*)((const char*)s_p + row * 128 + ((k0 * 64 + l4 * 16) ^ ((row & 7) << 4)));
        }
#pragma unroll
        for (int fn = 0; fn < 2; ++fn) {
            int hd = wid * 32 + fn * 16 + l15;
            bv2[fn] = *(const bf16x8*)((const char*)s_v + hd * 128 + ((k0 * 64 + l4 * 16) ^ ((hd & 7) << 4)));
        }
        __builtin_amdgcn_s_setprio(1);
#pragma unroll
        for (int fn = 0; fn < 2; ++fn)
#pragma unroll
            for (int tm = 0; tm < 4; ++tm) o[fn][tm] = MFMA16(bv2[fn], ap[tm], o[fn][tm]);
        __builtin_amdgcn_s_setprio(0);
    }
#pragma unroll
    for (int tm = 0; tm < 4; ++tm) {
        if (tm * 16 + l15 < 49) {
            short* dst = aout + (size_t)trow[tm] * 512 + head * 128 + wid * 32 + l4 * 4;
#pragma unroll
            for (int fn = 0; fn < 2; ++fn) {
                u32x2 pv = { cvtpk(o[fn][tm][0], o[fn][tm][1]), cvtpk(o[fn][tm][2], o[fn][tm][3]) };
                *(u32x2*)(dst + fn * 16) = pv;
            }
        }
    }
}

// ---------- fused proj+LN2+mlp1 (round-10, unchanged) ----------
__global__ __launch_bounds__(256, 2) void projmlp_kernel(const short* __restrict__ A,
                                                         const short* __restrict__ woT,
                                                         const short* __restrict__ wm1T,
                                                         const float* __restrict__ b_o,
                                                         const float* __restrict__ ga2,
                                                         const float* __restrict__ be2,
                                                         const float* __restrict__ b1,
                                                         float* __restrict__ outf,
                                                         short* __restrict__ hid) {
    __shared__ char smem[65536];
    float* red = (float*)(smem + 32768);

    const int tid = threadIdx.x, wid = tid >> 6, lane = tid & 63;
    const int wr = wid >> 1, wc = wid & 1;
    const int l15 = lane & 15, l4 = lane >> 4;
    const int m0 = blockIdx.x * 128;

    auto stage = [&](int kc, int bi) {
#pragma unroll
        for (int it = 0; it < 4; ++it) {
            int slot = it * 256 + tid;
            int row = slot >> 3, scol = slot & 7;
            int colb = (scol * 16) ^ ((row & 7) << 4);
            gload16((const char*)(A + (size_t)(m0 + row) * 512 + kc * 64) + colb,
                    (char*)smem + bi * 32768 + (it * 256 + wid * 64) * 16);
        }
#pragma unroll
        for (int it = 0; it < 4; ++it) {
            int slot = it * 256 + tid;
            int row = slot >> 3, scol = slot & 7;
            int colb = (scol * 16) ^ ((row & 7) << 4);
            gload16((const char*)(woT + (size_t)row * 512 + kc * 64) + colb,
                    (char*)smem + bi * 32768 + 16384 + (it * 256 + wid * 64) * 16);
        }
    };

    const f32x4 zero4 = {0.f, 0.f, 0.f, 0.f};
    f32x4 acc[4][4];
#pragma unroll
    for (int nf = 0; nf < 4; ++nf)
#pragma unroll
        for (int tm = 0; tm < 4; ++tm) acc[nf][tm] = zero4;

    stage(0, 0);
    __syncthreads();
#pragma unroll
    for (int kc = 0; kc < 8; ++kc) {
        if (kc + 1 < 8) stage(kc + 1, (kc + 1) & 1);
        const char* bufA = (const char*)smem + (kc & 1) * 32768;
        const char* bufB = bufA + 16384;
#pragma unroll
        for (int ks = 0; ks < 2; ++ks) {
            bf16x8 a[4], bfr[4];
#pragma unroll
            for (int tm = 0; tm < 4; ++tm) {
                int row = wr * 64 + tm * 16 + l15;
                a[tm] = *(const bf16x8*)(bufA + row * 128 + ((ks * 64 + l4 * 16) ^ ((row & 7) << 4)));
            }
#pragma unroll
            for (int nf = 0; nf < 4; ++nf) {
                int row = wc * 64 + nf * 16 + l15;
                bfr[nf] = *(const bf16x8*)(bufB + row * 128 + ((ks * 64 + l4 * 16) ^ ((row & 7) << 4)));
            }
            __builtin_amdgcn_s_setprio(1);
#pragma unroll
            for (int nf = 0; nf < 4; ++nf)
#pragma unroll
                for (int tm = 0; tm < 4; ++tm) acc[nf][tm] = MFMA16(bfr[nf], a[tm], acc[nf][tm]);
            __builtin_amdgcn_s_setprio(0);
        }
        __syncthreads();
    }

    f32x4 bv4[4];
#pragma unroll
    for (int nf = 0; nf < 4; ++nf)
        bv4[nf] = *(const f32x4*)(b_o + wc * 64 + nf * 16 + l4 * 4);

    float s1[4], s2[4];
#pragma unroll
    for (int tm = 0; tm < 4; ++tm) {
        int row = m0 + wr * 64 + tm * 16 + l15;
        float a1 = 0.f, a2 = 0.f;
#pragma unroll
        for (int nf = 0; nf < 4; ++nf) {
            f32x4 rs = *(const f32x4*)(outf + (size_t)row * 128 + wc * 64 + nf * 16 + l4 * 4);
#pragma unroll
            for (int r = 0; r < 4; ++r) {
                float v = acc[nf][tm][r] + bv4[nf][r] + rs[r];
                acc[nf][tm][r] = v;
                a1 += v; a2 += v * v;
            }
        }
        s1[tm] = a1; s2[tm] = a2;
    }
#pragma unroll
    for (int tm = 0; tm < 4; ++tm) {
        s1[tm] += __shfl_xor(s1[tm], 16); s1[tm] += __shfl_xor(s1[tm], 32);
        s2[tm] += __shfl_xor(s2[tm], 16); s2[tm] += __shfl_xor(s2[tm], 32);
    }
    if (l4 == 0) {
#pragma unroll
        for (int tm = 0; tm < 4; ++tm) {
            int lrow = wr * 64 + tm * 16 + l15;
            red[lrow * 4 + wc * 2] = s1[tm];
            red[lrow * 4 + wc * 2 + 1] = s2[tm];
        }
    }
    __syncthreads();

    float mean[4], rstd[4];
#pragma unroll
    for (int tm = 0; tm < 4; ++tm) {
        int lrow = wr * 64 + tm * 16 + l15;
        f32x4 rd = *(const f32x4*)(red + lrow * 4);
        float t1 = rd[0] + rd[2], t2 = rd[1] + rd[3];
        mean[tm] = t1 * (1.f / 128.f);
        float var = t2 * (1.f / 128.f) - mean[tm] * mean[tm];
        rstd[tm] = rsqrtf(var + 1e-5f);
    }
    __syncthreads();

#pragma unroll
    for (int tm = 0; tm < 4; ++tm) {
        int lrow = wr * 64 + tm * 16 + l15;
        int row = m0 + lrow;
#pragma unroll
        for (int nf = 0; nf < 4; ++nf) {
            int col0 = wc * 64 + nf * 16 + l4 * 4;
            *(f32x4*)(outf + (size_t)row * 128 + col0) = acc[nf][tm];
            f32x4 gg = *(const f32x4*)(ga2 + col0);
            f32x4 bb = *(const f32x4*)(be2 + col0);
            float w0 = (acc[nf][tm][0] - mean[tm]) * rstd[tm] * gg[0] + bb[0];
            float w1 = (acc[nf][tm][1] - mean[tm]) * rstd[tm] * gg[1] + bb[1];
            float w2 = (acc[nf][tm][2] - mean[tm]) * rstd[tm] * gg[2] + bb[2];
            float w3 = (acc[nf][tm][3] - mean[tm]) * rstd[tm] * gg[3] + bb[3];
            u32x2 pb = { cvtpk(w0, w1), cvtpk(w2, w3) };
            *(u32x2*)((char*)smem + lrow * 256 + ((col0 * 2) ^ ((lrow & 7) << 4))) = pb;
        }
    }
    __syncthreads();

    for (int hc = 0; hc < 4; ++hc) {
#pragma unroll
        for (int it = 0; it < 8; ++it) {
            int slot = it * 256 + tid;
            int row = slot >> 4, scol = slot & 15;
            int colb = (scol * 16) ^ ((row & 7) << 4);
            gload16((const char*)(wm1T + (size_t)(hc * 128 + row) * 128) + colb,
                    (char*)smem + 32768 + (it * 256 + wid * 64) * 16);
        }
        __syncthreads();

        f32x4 acc2[4][4];
#pragma unroll
        for (int nf = 0; nf < 4; ++nf)
#pragma unroll
            for (int tm = 0; tm < 4; ++tm) acc2[nf][tm] = zero4;
#pragma unroll
        for (int ks = 0; ks < 4; ++ks) {
            bf16x8 a[4], bfr[4];
#pragma unroll
            for (int tm = 0; tm < 4; ++tm) {
                int row = wr * 64 + tm * 16 + l15;
                a[tm] = *(const bf16x8*)((const char*)smem + row * 256 + ((ks * 64 + l4 * 16) ^ ((row & 7) << 4)));
            }
#pragma unroll
            for (int nf = 0; nf < 4; ++nf) {
                int hrow = wc * 64 + nf * 16 + l15;
                bfr[nf] = *(const bf16x8*)((const char*)smem + 32768 + hrow * 256 + ((ks * 64 + l4 * 16) ^ ((hrow & 7) << 4)));
            }
            __builtin_amdgcn_s_setprio(1);
#pragma unroll
            for (int nf = 0; nf < 4; ++nf)
#pragma unroll
                for (int tm = 0; tm < 4; ++tm) acc2[nf][tm] = MFMA16(bfr[nf], a[tm], acc2[nf][tm]);
            __builtin_amdgcn_s_setprio(0);
        }

        f32x4 b14[4];
#pragma unroll
        for (int nf = 0; nf < 4; ++nf)
            b14[nf] = *(const f32x4*)(b1 + hc * 128 + wc * 64 + nf * 16 + l4 * 4);
#pragma unroll
        for (int tm = 0; tm < 4; ++tm) {
            int row = m0 + wr * 64 + tm * 16 + l15;
#pragma unroll
            for (int nf = 0; nf < 4; ++nf) {
                float v0 = gelu(acc2[nf][tm][0] + b14[nf][0]);
                float v1 = gelu(acc2[nf][tm][1] + b14[nf][1]);
                float v2 = gelu(acc2[nf][tm][2] + b14[nf][2]);
                float v3 = gelu(acc2[nf][tm][3] + b14[nf][3]);
                u32x2 pv = { cvtpk(v0, v1), cvtpk(v2, v3) };
                *(u32x2*)(hid + (size_t)row * 512 + hc * 128 + wc * 64 + nf * 16 + l4 * 4) = pv;
            }
        }
        __syncthreads();
    }
}

// ---------- GEMM (round-7): 128x128x512, DB pipeline; MODE 1 = resid+LN, 2 = resid->f32 ----------
template <int MODE>
__global__ __launch_bounds__(256, 2) void gemm4_kernel(const short* __restrict__ A,
                                                       const short* __restrict__ BT,
                                                       const float* __restrict__ bias,
                                                       const float* __restrict__ g,
                                                       const float* __restrict__ bta,
                                                       float* __restrict__ outf,
                                                       short* __restrict__ outb) {
    __shared__ char smem[65536];
    float* red = (float*)smem;

    const int tid = threadIdx.x, wid = tid >> 6, lane = tid & 63;
    const int wr = wid >> 1, wc = wid & 1;
    const int l15 = lane & 15, l4 = lane >> 4;
    const int m0 = blockIdx.x * 128;

    auto stage = [&](int kc, int bi) {
#pragma unroll
        for (int it = 0; it < 4; ++it) {
            int slot = it * 256 + tid;
            int row = slot >> 3, scol = slot & 7;
            int colb = (scol * 16) ^ ((row & 7) << 4);
            gload16((const char*)(A + (size_t)(m0 + row) * 512 + kc * 64) + colb,
                    (char*)smem + bi * 32768 + (it * 256 + wid * 64) * 16);
        }
#pragma unroll
        for (int it = 0; it < 4; ++it) {
            int slot = it * 256 + tid;
            int row = slot >> 3, scol = slot & 7;
            int colb = (scol * 16) ^ ((row & 7) << 4);
            gload16((const char*)(BT + (size_t)row * 512 + kc * 64) + colb,
                    (char*)smem + bi * 32768 + 16384 + (it * 256 + wid * 64) * 16);
        }
    };

    const f32x4 zero4 = {0.f, 0.f, 0.f, 0.f};
    f32x4 acc[4][4];
#pragma unroll
    for (int nf = 0; nf < 4; ++nf)
#pragma unroll
        for (int tm = 0; tm < 4; ++tm) acc[nf][tm] = zero4;

    stage(0, 0);
    __syncthreads();
#pragma unroll
    for (int kc = 0; kc < 8; ++kc) {
        if (kc + 1 < 8) stage(kc + 1, (kc + 1) & 1);
        const char* bufA = (const char*)smem + (kc & 1) * 32768;
        const char* bufB = bufA + 16384;
#pragma unroll
        for (int ks = 0; ks < 2; ++ks) {
            bf16x8 a[4], bfr[4];
#pragma unroll
            for (int tm = 0; tm < 4; ++tm) {
                int row = wr * 64 + tm * 16 + l15;
                a[tm] = *(const bf16x8*)(bufA + row * 128 + ((ks * 64 + l4 * 16) ^ ((row & 7) << 4)));
            }
#pragma unroll
            for (int nf = 0; nf < 4; ++nf) {
                int row = wc * 64 + nf * 16 + l15;
                bfr[nf] = *(const bf16x8*)(bufB + row * 128 + ((ks * 64 + l4 * 16) ^ ((row & 7) << 4)));
            }
            __builtin_amdgcn_s_setprio(1);
#pragma unroll
            for (int nf = 0; nf < 4; ++nf)
#pragma unroll
                for (int tm = 0; tm < 4; ++tm) acc[nf][tm] = MFMA16(bfr[nf], a[tm], acc[nf][tm]);
            __builtin_amdgcn_s_setprio(0);
        }
        __syncthreads();
    }

    f32x4 bv4[4];
#pragma unroll
    for (int nf = 0; nf < 4; ++nf)
        bv4[nf] = *(const f32x4*)(bias + wc * 64 + nf * 16 + l4 * 4);

    float s1[4], s2[4];
#pragma unroll
    for (int tm = 0; tm < 4; ++tm) {
        int row = m0 + wr * 64 + tm * 16 + l15;
        float a1 = 0.f, a2 = 0.f;
#pragma unroll
        for (int nf = 0; nf < 4; ++nf) {
            f32x4 rs = *(const f32x4*)(outf + (size_t)row * 128 + wc * 64 + nf * 16 + l4 * 4);
#pragma unroll
            for (int r = 0; r < 4; ++r) {
                float v = acc[nf][tm][r] + bv4[nf][r] + rs[r];
                acc[nf][tm][r] = v;
                a1 += v; a2 += v * v;
            }
        }
        s1[tm] = a1; s2[tm] = a2;
    }

    if (MODE == 1) {
#pragma unroll
        for (int tm = 0; tm < 4; ++tm) {
            s1[tm] += __shfl_xor(s1[tm], 16); s1[tm] += __shfl_xor(s1[tm], 32);
            s2[tm] += __shfl_xor(s2[tm], 16); s2[tm] += __shfl_xor(s2[tm], 32);
        }
        if (l4 == 0) {
#pragma unroll
            for (int tm = 0; tm < 4; ++tm) {
                int lrow = wr * 64 + tm * 16 + l15;
                red[lrow * 4 + wc * 2] = s1[tm];
                red[lrow * 4 + wc * 2 + 1] = s2[tm];
            }
        }
        __syncthreads();
    }

#pragma unroll
    for (int tm = 0; tm < 4; ++tm) {
        int lrow = wr * 64 + tm * 16 + l15;
        int row = m0 + lrow;
        float mean = 0.f, rstd = 0.f;
        if (MODE == 1) {
            f32x4 rd = *(const f32x4*)(red + lrow * 4);
            float t1 = rd[0] + rd[2], t2 = rd[1] + rd[3];
            mean = t1 * (1.f / 128.f);
            float var = t2 * (1.f / 128.f) - mean * mean;
            rstd = rsqrtf(var + 1e-5f);
        }
#pragma unroll
        for (int nf = 0; nf < 4; ++nf) {
            int col0 = wc * 64 + nf * 16 + l4 * 4;
            *(f32x4*)(outf + (size_t)row * 128 + col0) = acc[nf][tm];
            if (MODE == 1) {
                f32x4 gg = *(const f32x4*)(g + col0);
                f32x4 bb = *(const f32x4*)(bta + col0);
                float w0 = (acc[nf][tm][0] - mean) * rstd * gg[0] + bb[0];
                float w1 = (acc[nf][tm][1] - mean) * rstd * gg[1] + bb[1];
                float w2 = (acc[nf][tm][2] - mean) * rstd * gg[2] + bb[2];
                float w3 = (acc[nf][tm][3] - mean) * rstd * gg[3] + bb[3];
                u32x2 pb = { cvtpk(w0, w1), cvtpk(w2, w3) };
                *(u32x2*)(outb + (size_t)row * 128 + col0) = pb;
            }
        }
    }
}

extern "C" void kernel_launch(void* const* d_in, const int* in_sizes, int n_in,
                              void* d_out, int out_size, void* d_ws, size_t ws_size,
                              hipStream_t stream) {
    const float* x = (const float*)d_in[0];
    const float* w_pe = (const float*)d_in[1];
    const float* b_pe = (const float*)d_in[2];
    const float* P[24];
    for (int i = 0; i < 24; ++i) P[i] = (const float*)d_in[3 + i];
    // per layer s: [s*12+0..11] = ga1, be1, w_qkv, pos, w_o, b_o, ga2, be2, w_m1, b_m1, w_m2, b_m2

    float* out = (float*)d_out;
    const size_t TOK = 100352;

    short* xn = (short*)d_ws;          // TOK*128 bf16
    short* abuf = xn + TOK * 128;      // TOK*512 bf16
    short* wqkv = abuf + TOK * 512;    // 1536x128
    short* wo = wqkv + 196608;         // 128x512
    short* wm1 = wo + 65536;           // 512x128
    short* wm2 = wm1 + 65536;          // 128x512
    short* mtb = wm2 + 65536;          // 4x128x128 bf16
    float* tab = (float*)(mtb + 65536);  // 5*4096 f32
    short* zpad = (short*)(tab + 5 * 4096);  // 256B zeros

    hipMemsetAsync(zpad, 0, 256, stream);
    tabgen_kernel<<<5, 256, 0, stream>>>(P[3], P[15], tab);

    // patch embed + LN1a
    patchln_kernel<<<50176, 256, 0, stream>>>(x, w_pe, b_pe, P[0], P[1], out, xn);

    for (int s = 0; s < 2; ++s) {
        wconv_kernel<<<1536, 256, 0, stream>>>(P[s * 12 + 2], P[s * 12 + 4], P[s * 12 + 8], P[s * 12 + 10],
                                               wqkv, wo, wm1, wm2);
        mtgen_kernel<<<512, 128, 0, stream>>>(P[s * 12 + 2], mtb);

        if (s == 0)
            attn_kernel<0><<<8192, 256, 0, stream>>>(xn, wqkv, mtb, tab, zpad, abuf);
        else
            attn_kernel<1><<<8192, 256, 0, stream>>>(xn, wqkv, mtb, tab, zpad, abuf);

        // proj + residual + LN2 + mlp1 + GELU -> out f32, hidden in abuf
        projmlp_kernel<<<784, 256, 0, stream>>>(
            abuf, wo, wm1, P[s * 12 + 5], P[s * 12 + 6], P[s * 12 + 7], P[s * 12 + 9], out, abuf);

        // mlp2 + residual (+LN1 of next layer for s==0)
        if (s == 0)
            gemm4_kernel<1><<<784, 256, 0, stream>>>(
                abuf, wm2, P[11], P[12], P[13], out, xn);
        else
            gemm4_kernel<2><<<784, 256, 0, stream>>>(
                abuf, wm2, P[23], nullptr, nullptr, out, nullptr);
    }
}

// Round 18
// 549.850 us; speedup vs baseline: 1.0289x; 1.0289x over previous
//
#include <hip/hip_runtime.h>

typedef __attribute__((ext_vector_type(8))) short bf16x8;
typedef __attribute__((ext_vector_type(4))) short bf16x4;
typedef __attribute__((ext_vector_type(4))) float f32x4;
typedef __attribute__((ext_vector_type(2))) unsigned u32x2;

#define MFMA16(a, b, c) __builtin_amdgcn_mfma_f32_16x16x32_bf16(a, b, c, 0, 0, 0)

static __device__ __forceinline__ short f2bf(float f) {
    union { float f; unsigned u; } x; x.f = f;
    unsigned r = x.u + 0x7FFFu + ((x.u >> 16) & 1u);
    return (short)(r >> 16);
}

static __device__ __forceinline__ unsigned cvtpk(float lo, float hi) {
    unsigned r;
    asm("v_cvt_pk_bf16_f32 %0, %1, %2" : "=v"(r) : "v"(lo), "v"(hi));
    return r;
}

static __device__ __forceinline__ void gload16(const void* g, void* l) {
    __builtin_amdgcn_global_load_lds((const __attribute__((address_space(1))) void*)g,
                                     (__attribute__((address_space(3))) void*)l, 16, 0, 0);
}

static __device__ __forceinline__ float gelu(float t) {
    return 0.5f * t * (1.f + erff(t * 0.70710678118f));
}

// ---------- all 4 weight transposes for one layer in one launch ----------
__global__ void wconv_kernel(const float* __restrict__ i_qkv, const float* __restrict__ i_o,
                             const float* __restrict__ i_m1, const float* __restrict__ i_m2,
                             short* __restrict__ wqkv, short* __restrict__ wo,
                             short* __restrict__ wm1, short* __restrict__ wm2) {
    int idx = blockIdx.x * 256 + threadIdx.x;
    if (idx < 196608) {                       // qkv: (128,1536) -> (1536,128)
        int k = idx & 127, n = idx >> 7;
        wqkv[idx] = f2bf(i_qkv[k * 1536 + n]);
    } else if (idx < 262144) {                // w_o: (512,128) -> (128,512)
        int l = idx - 196608; int k = l & 511, n = l >> 9;
        wo[l] = f2bf(i_o[k * 128 + n]);
    } else if (idx < 327680) {                // w_m1: (128,512) -> (512,128)
        int l = idx - 262144; int k = l & 127, n = l >> 7;
        wm1[l] = f2bf(i_m1[k * 512 + n]);
    } else {                                  // w_m2: (512,128) -> (128,512)
        int l = idx - 327680; int k = l & 511, n = l >> 9;
        wm2[l] = f2bf(i_m2[k * 128 + n]);
    }
}

// ---------- MT[h][e][d] = SC * sum_o Wq[d,o]*Wk[e,o]  (dots = X M X^T) ----------
__global__ __launch_bounds__(128) void mtgen_kernel(const float* __restrict__ wqkv,
                                                    short* __restrict__ mt) {
    const int h = blockIdx.x >> 7, e = blockIdx.x & 127;
    __shared__ float s_wk[128];
    const int d = threadIdx.x;
    s_wk[d] = wqkv[(size_t)e * 1536 + 512 + h * 128 + d];
    __syncthreads();
    const float* wq = wqkv + (size_t)d * 1536 + h * 128;
    float acc = 0.f;
#pragma unroll
    for (int o = 0; o < 128; ++o) acc += wq[o] * s_wk[o];
    mt[(size_t)(h * 128 + e) * 128 + d] = f2bf(acc * 0.08838834764831845f);
}

// ---------- bias+mask table: tab[5][64][64] ----------
__global__ void tabgen_kernel(const float* __restrict__ pos_a, const float* __restrict__ pos_b,
                              float* __restrict__ tab) {
    int v = blockIdx.x;
    const float* pos = (v == 0) ? pos_a : pos_b;
    for (int e = threadIdx.x; e < 4096; e += 256) {
        int row = e >> 6, key = e & 63;
        float val;
        if (key >= 49) val = -1e9f;
        else if (row >= 49) val = 0.f;
        else {
            int qi = row / 7, qj = row - qi * 7, ki = key / 7, kj = key - ki * 7;
            val = pos[(ki - qi + 6) * 13 + (kj - qj + 6)];
            if (v >= 1) {
                bool wh7 = (v - 1) & 2, ww7 = (v - 1) & 1;
                if (wh7 && ((qi >= 4) != (ki >= 4))) val += -1e9f;
                if (ww7 && ((qj >= 4) != (kj >= 4))) val += -1e9f;
            }
        }
        tab[v * 4096 + e] = val;
    }
}

// ---------- patch embed + LN1a: out f32 + xn bf16 ----------
__global__ __launch_bounds__(256) void patchln_kernel(const float* __restrict__ x,
                                                      const float* __restrict__ w,
                                                      const float* __restrict__ bias,
                                                      const float* __restrict__ g,
                                                      const float* __restrict__ bta,
                                                      float* __restrict__ out,
                                                      short* __restrict__ xn) {
    __shared__ float s_in[2][48];
    __shared__ float red[2][2][2];
    const int tid = threadIdx.x;
    const int half = tid >> 7, c = tid & 127;
    const int winh = (tid >> 6) & 1, lane = tid & 63;
    const int t = blockIdx.x * 2 + half;
    const int b = t / 3136, rem = t - b * 3136;
    const int hp = rem / 56, wp = rem - hp * 56;
    if (c < 48) {
        int cin = c >> 4, py = (c >> 2) & 3, px = c & 3;
        s_in[half][c] = x[((size_t)(b * 3 + cin) * 224 + hp * 4 + py) * 224 + wp * 4 + px];
    }
    __syncthreads();
    float acc = bias[c];
#pragma unroll
    for (int k = 0; k < 48; ++k) acc += s_in[half][k] * w[k * 128 + c];
    out[(size_t)t * 128 + c] = acc;
    float s1 = acc, s2 = acc * acc;
#pragma unroll
    for (int o = 32; o > 0; o >>= 1) { s1 += __shfl_xor(s1, o); s2 += __shfl_xor(s2, o); }
    if (lane == 0) { red[half][winh][0] = s1; red[half][winh][1] = s2; }
    __syncthreads();
    s1 = red[half][0][0] + red[half][1][0];
    s2 = red[half][0][1] + red[half][1][1];
    float mean = s1 * (1.f / 128.f);
    float var = s2 * (1.f / 128.f) - mean * mean;
    float rstd = rsqrtf(var + 1e-5f);
    xn[(size_t)t * 128 + c] = f2bf((acc - mean) * rstd * g[c] + bta[c]);
}

// ---------- fused window attention v12: dots = X M X^T, 4-barrier proven skeleton ----------
template <int SHIFTED>
__global__ __launch_bounds__(256, 3) void attn_kernel(const short* __restrict__ xn,
                                                      const short* __restrict__ wqkvT,
                                                      const short* __restrict__ mt,
                                                      const float* __restrict__ tab,
                                                      const short* __restrict__ zpad,
                                                      short* __restrict__ aout) {
    __shared__ short smem[24576];               // 48 KB
    short* s_x = smem;                          // X: 64 x 256B (swizzled); after bar3: P 64 x 128B
    short* s_T = smem + 8192;                   // T = X@M: 64 x 256B
    short* s_v = smem + 16384;                  // V^T: 128 x 128B
    short* s_p = smem;                          // P overlays s_x after bar3

    const int tid = threadIdx.x;
    const int wid = tid >> 6, lane = tid & 63;
    const int l15 = lane & 15, l4 = lane >> 4, klo = l4 * 8;
    const int bid = blockIdx.x;
    // win-fastest: the 4 heads of a window sit 64 apart -> same XCD (L2 locality)
    const int win = bid & 63, head = (bid >> 6) & 3, b = bid >> 8;
    const int wh = win >> 3, ww = win & 7;

    // ---- stage X window into swizzled s_x via global_load_lds ----
#pragma unroll
    for (int it = 0; it < 4; ++it) {
        int slot = it * 256 + tid;
        int row = slot >> 4, scol = slot & 15;
        int colb = (scol * 16) ^ ((row & 7) << 4);
        const char* g;
        if (row < 49) {
            int wi = (row * 37) >> 8, wj = row - wi * 7;
            int hh = wh * 7 + wi, wp = ww * 7 + wj;
            if (SHIFTED) { hh += 3; if (hh >= 56) hh -= 56; wp += 3; if (wp >= 56) wp -= 56; }
            int t = (b * 56 + hh) * 56 + wp;
            g = (const char*)(xn + (size_t)t * 128) + colb;
        } else {
            g = (const char*)zpad + colb;
        }
        gload16(g, (char*)smem + (it * 256 + wid * 64) * 16);
    }
    __syncthreads();   // bar1

    const f32x4 zero4 = {0.f, 0.f, 0.f, 0.f};

    // ---- merged T = X@M  and  V = X@Wv (shared X fragments) ----
    {
        const short* Mh = mt + (size_t)head * 16384;
        const short* Wv = wqkvT + (size_t)(1024 + head * 128) * 128;
        f32x4 at[2][4], av[4][2];
#pragma unroll
        for (int mw = 0; mw < 2; ++mw)
#pragma unroll
            for (int j = 0; j < 4; ++j) at[mw][j] = zero4;
#pragma unroll
        for (int m = 0; m < 4; ++m)
#pragma unroll
            for (int n = 0; n < 2; ++n) av[m][n] = zero4;
#pragma unroll
        for (int k0 = 0; k0 < 4; ++k0) {
            bf16x8 bx[4], awt[2], bwv[2];
#pragma unroll
            for (int j = 0; j < 4; ++j) {
                int row = j * 16 + l15;
                bx[j] = *(const bf16x8*)((const char*)s_x + row * 256 + ((k0 * 64 + l4 * 16) ^ ((row & 7) << 4)));
            }
#pragma unroll
            for (int mw = 0; mw < 2; ++mw)
                awt[mw] = *(const bf16x8*)(Mh + (size_t)(wid * 32 + mw * 16 + l15) * 128 + k0 * 32 + klo);
#pragma unroll
            for (int n = 0; n < 2; ++n)
                bwv[n] = *(const bf16x8*)(Wv + (size_t)(wid * 32 + n * 16 + l15) * 128 + k0 * 32 + klo);
            __builtin_amdgcn_s_setprio(1);
#pragma unroll
            for (int mw = 0; mw < 2; ++mw)
#pragma unroll
                for (int j = 0; j < 4; ++j) at[mw][j] = MFMA16(awt[mw], bx[j], at[mw][j]);
#pragma unroll
            for (int m = 0; m < 4; ++m)
#pragma unroll
                for (int n = 0; n < 2; ++n) av[m][n] = MFMA16(bx[m], bwv[n], av[m][n]);
            __builtin_amdgcn_s_setprio(0);
        }
        // T store (token-major 256B rows)
#pragma unroll
        for (int mw = 0; mw < 2; ++mw)
#pragma unroll
            for (int j = 0; j < 4; ++j) {
                u32x2 pq = { cvtpk(at[mw][j][0], at[mw][j][1]), cvtpk(at[mw][j][2], at[mw][j][3]) };
                int row = j * 16 + l15;
                *(u32x2*)((char*)s_T + row * 256 + ((wid * 64 + mw * 32 + l4 * 8) ^ ((row & 7) << 4))) = pq;
            }
        // V^T store (head-dim-major 128B rows)
#pragma unroll
        for (int m = 0; m < 4; ++m)
#pragma unroll
            for (int n = 0; n < 2; ++n) {
                u32x2 pv = { cvtpk(av[m][n][0], av[m][n][1]), cvtpk(av[m][n][2], av[m][n][3]) };
                int hd = wid * 32 + n * 16 + l15;
                *(u32x2*)((char*)s_v + hd * 128 + ((m * 32 + l4 * 8) ^ ((hd & 7) << 4))) = pv;
            }
    }
    __syncthreads();   // bar2: T and V visible

    // ---- dots^T = mfma(X, T): lane holds query-row qrow's 16 scores ----
    const int qrow = wid * 16 + l15;
    f32x4 dt[4];
#pragma unroll
    for (int m = 0; m < 4; ++m) dt[m] = zero4;
#pragma unroll
    for (int k0 = 0; k0 < 4; ++k0) {
        bf16x8 bq = *(const bf16x8*)((const char*)s_T + qrow * 256 + ((k0 * 64 + l4 * 16) ^ ((qrow & 7) << 4)));
        __builtin_amdgcn_s_setprio(1);
#pragma unroll
        for (int m = 0; m < 4; ++m) {
            int krow = m * 16 + l15;
            bf16x8 akf = *(const bf16x8*)((const char*)s_x + krow * 256 + ((k0 * 64 + l4 * 16) ^ ((krow & 7) << 4)));
            dt[m] = MFMA16(akf, bq, dt[m]);
        }
        __builtin_amdgcn_s_setprio(0);
    }
    __syncthreads();   // bar3: ALL waves done reading s_x -> region dead, safe for P

    // ---- in-register softmax (SC folded into M); P -> dead s_x region ----
    const int variant = SHIFTED ? (1 + ((wh == 7) ? 2 : 0) + ((ww == 7) ? 1 : 0)) : 0;
    const float* tv = tab + variant * 4096 + qrow * 64;
    float p[4][4];
    float mx = -3.0e38f;
#pragma unroll
    for (int m = 0; m < 4; ++m) {
        f32x4 tb = *(const f32x4*)(tv + m * 16 + l4 * 4);
#pragma unroll
        for (int r = 0; r < 4; ++r) {
            float d = dt[m][r] + tb[r];
            p[m][r] = d;
            mx = fmaxf(mx, d);
        }
    }
    mx = fmaxf(mx, __shfl_xor(mx, 16));
    mx = fmaxf(mx, __shfl_xor(mx, 32));
    float sum = 0.f;
#pragma unroll
    for (int m = 0; m < 4; ++m)
#pragma unroll
        for (int r = 0; r < 4; ++r) { p[m][r] = __expf(p[m][r] - mx); sum += p[m][r]; }
    sum += __shfl_xor(sum, 16);
    sum += __shfl_xor(sum, 32);
    float inv = 1.f / sum;
#pragma unroll
    for (int m = 0; m < 4; ++m) {
        u32x2 pv = { cvtpk(p[m][0] * inv, p[m][1] * inv), cvtpk(p[m][2] * inv, p[m][3] * inv) };
        *(u32x2*)((char*)s_p + qrow * 128 + ((m * 32 + l4 * 8) ^ ((qrow & 7) << 4))) = pv;
    }
    __syncthreads();   // bar4: P visible to all waves

    // ---- out = P @ V ----
    f32x4 o[4][2];
#pragma unroll
    for (int m = 0; m < 4; ++m)
#pragma unroll
        for (int n = 0; n < 2; ++n) o[m][n] = zero4;
#pragma unroll
    for (int k0 = 0; k0 < 2; ++k0) {
        bf16x8 ap[4], bv[2];
#pragma unroll
        for (int m = 0; m < 4; ++m) {
            int row = m * 16 + l15;
            ap[m] = *(const bf16x8*)((const char*)s_p + row * 128 + ((k0 * 64 + l4 * 16) ^ ((row & 7) << 4)));
        }
#pragma unroll
        for (int n = 0; n < 2; ++n) {
            int hd = wid * 32 + n * 16 + l15;
            bv[n] = *(const bf16x8*)((const char*)s_v + hd * 128 + ((k0 * 64 + l4 * 16) ^ ((hd & 7) << 4)));
        }
        __builtin_amdgcn_s_setprio(1);
#pragma unroll
        for (int m = 0; m < 4; ++m)
#pragma unroll
            for (int n = 0; n < 2; ++n) o[m][n] = MFMA16(ap[m], bv[n], o[m][n]);
        __builtin_amdgcn_s_setprio(0);
    }
#pragma unroll
    for (int m = 0; m < 4; ++m) {
#pragma unroll
        for (int r = 0; r < 4; ++r) {
            int rl = m * 16 + l4 * 4 + r;
            if (rl < 49) {
                int wi = (rl * 37) >> 8, wj = rl - wi * 7;
                int hh = wh * 7 + wi, wp = ww * 7 + wj;
                if (SHIFTED) { hh += 3; if (hh >= 56) hh -= 56; wp += 3; if (wp >= 56) wp -= 56; }
                size_t t = (size_t)(b * 56 + hh) * 56 + wp;
                aout[t * 512 + head * 128 + wid * 32 + l15] = f2bf(o[m][0][r]);
                aout[t * 512 + head * 128 + wid * 32 + 16 + l15] = f2bf(o[m][1][r]);
            }
        }
    }
}

// ---------- fused proj+LN2+mlp1 (round-10, unchanged) ----------
__global__ __launch_bounds__(256, 2) void projmlp_kernel(const short* __restrict__ A,
                                                         const short* __restrict__ woT,
                                                         const short* __restrict__ wm1T,
                                                         const float* __restrict__ b_o,
                                                         const float* __restrict__ ga2,
                                                         const float* __restrict__ be2,
                                                         const float* __restrict__ b1,
                                                         float* __restrict__ outf,
                                                         short* __restrict__ hid) {
    __shared__ char smem[65536];
    float* red = (float*)(smem + 32768);

    const int tid = threadIdx.x, wid = tid >> 6, lane = tid & 63;
    const int wr = wid >> 1, wc = wid & 1;
    const int l15 = lane & 15, l4 = lane >> 4;
    const int m0 = blockIdx.x * 128;

    auto stage = [&](int kc, int bi) {
#pragma unroll
        for (int it = 0; it < 4; ++it) {
            int slot = it * 256 + tid;
            int row = slot >> 3, scol = slot & 7;
            int colb = (scol * 16) ^ ((row & 7) << 4);
            gload16((const char*)(A + (size_t)(m0 + row) * 512 + kc * 64) + colb,
                    (char*)smem + bi * 32768 + (it * 256 + wid * 64) * 16);
        }
#pragma unroll
        for (int it = 0; it < 4; ++it) {
            int slot = it * 256 + tid;
            int row = slot >> 3, scol = slot & 7;
            int colb = (scol * 16) ^ ((row & 7) << 4);
            gload16((const char*)(woT + (size_t)row * 512 + kc * 64) + colb,
                    (char*)smem + bi * 32768 + 16384 + (it * 256 + wid * 64) * 16);
        }
    };

    const f32x4 zero4 = {0.f, 0.f, 0.f, 0.f};
    f32x4 acc[4][4];
#pragma unroll
    for (int nf = 0; nf < 4; ++nf)
#pragma unroll
        for (int tm = 0; tm < 4; ++tm) acc[nf][tm] = zero4;

    stage(0, 0);
    __syncthreads();
#pragma unroll
    for (int kc = 0; kc < 8; ++kc) {
        if (kc + 1 < 8) stage(kc + 1, (kc + 1) & 1);
        const char* bufA = (const char*)smem + (kc & 1) * 32768;
        const char* bufB = bufA + 16384;
#pragma unroll
        for (int ks = 0; ks < 2; ++ks) {
            bf16x8 a[4], bfr[4];
#pragma unroll
            for (int tm = 0; tm < 4; ++tm) {
                int row = wr * 64 + tm * 16 + l15;
                a[tm] = *(const bf16x8*)(bufA + row * 128 + ((ks * 64 + l4 * 16) ^ ((row & 7) << 4)));
            }
#pragma unroll
            for (int nf = 0; nf < 4; ++nf) {
                int row = wc * 64 + nf * 16 + l15;
                bfr[nf] = *(const bf16x8*)(bufB + row * 128 + ((ks * 64 + l4 * 16) ^ ((row & 7) << 4)));
            }
            __builtin_amdgcn_s_setprio(1);
#pragma unroll
            for (int nf = 0; nf < 4; ++nf)
#pragma unroll
                for (int tm = 0; tm < 4; ++tm) acc[nf][tm] = MFMA16(bfr[nf], a[tm], acc[nf][tm]);
            __builtin_amdgcn_s_setprio(0);
        }
        __syncthreads();
    }

    f32x4 bv4[4];
#pragma unroll
    for (int nf = 0; nf < 4; ++nf)
        bv4[nf] = *(const f32x4*)(b_o + wc * 64 + nf * 16 + l4 * 4);

    float s1[4], s2[4];
#pragma unroll
    for (int tm = 0; tm < 4; ++tm) {
        int row = m0 + wr * 64 + tm * 16 + l15;
        float a1 = 0.f, a2 = 0.f;
#pragma unroll
        for (int nf = 0; nf < 4; ++nf) {
            f32x4 rs = *(const f32x4*)(outf + (size_t)row * 128 + wc * 64 + nf * 16 + l4 * 4);
#pragma unroll
            for (int r = 0; r < 4; ++r) {
                float v = acc[nf][tm][r] + bv4[nf][r] + rs[r];
                acc[nf][tm][r] = v;
                a1 += v; a2 += v * v;
            }
        }
        s1[tm] = a1; s2[tm] = a2;
    }
#pragma unroll
    for (int tm = 0; tm < 4; ++tm) {
        s1[tm] += __shfl_xor(s1[tm], 16); s1[tm] += __shfl_xor(s1[tm], 32);
        s2[tm] += __shfl_xor(s2[tm], 16); s2[tm] += __shfl_xor(s2[tm], 32);
    }
    if (l4 == 0) {
#pragma unroll
        for (int tm = 0; tm < 4; ++tm) {
            int lrow = wr * 64 + tm * 16 + l15;
            red[lrow * 4 + wc * 2] = s1[tm];
            red[lrow * 4 + wc * 2 + 1] = s2[tm];
        }
    }
    __syncthreads();

    float mean[4], rstd[4];
#pragma unroll
    for (int tm = 0; tm < 4; ++tm) {
        int lrow = wr * 64 + tm * 16 + l15;
        f32x4 rd = *(const f32x4*)(red + lrow * 4);
        float t1 = rd[0] + rd[2], t2 = rd[1] + rd[3];
        mean[tm] = t1 * (1.f / 128.f);
        float var = t2 * (1.f / 128.f) - mean[tm] * mean[tm];
        rstd[tm] = rsqrtf(var + 1e-5f);
    }
    __syncthreads();

#pragma unroll
    for (int tm = 0; tm < 4; ++tm) {
        int lrow = wr * 64 + tm * 16 + l15;
        int row = m0 + lrow;
#pragma unroll
        for (int nf = 0; nf < 4; ++nf) {
            int col0 = wc * 64 + nf * 16 + l4 * 4;
            *(f32x4*)(outf + (size_t)row * 128 + col0) = acc[nf][tm];
            f32x4 gg = *(const f32x4*)(ga2 + col0);
            f32x4 bb = *(const f32x4*)(be2 + col0);
            float w0 = (acc[nf][tm][0] - mean[tm]) * rstd[tm] * gg[0] + bb[0];
            float w1 = (acc[nf][tm][1] - mean[tm]) * rstd[tm] * gg[1] + bb[1];
            float w2 = (acc[nf][tm][2] - mean[tm]) * rstd[tm] * gg[2] + bb[2];
            float w3 = (acc[nf][tm][3] - mean[tm]) * rstd[tm] * gg[3] + bb[3];
            u32x2 pb = { cvtpk(w0, w1), cvtpk(w2, w3) };
            *(u32x2*)((char*)smem + lrow * 256 + ((col0 * 2) ^ ((lrow & 7) << 4))) = pb;
        }
    }
    __syncthreads();

    for (int hc = 0; hc < 4; ++hc) {
#pragma unroll
        for (int it = 0; it < 8; ++it) {
            int slot = it * 256 + tid;
            int row = slot >> 4, scol = slot & 15;
            int colb = (scol * 16) ^ ((row & 7) << 4);
            gload16((const char*)(wm1T + (size_t)(hc * 128 + row) * 128) + colb,
                    (char*)smem + 32768 + (it * 256 + wid * 64) * 16);
        }
        __syncthreads();

        f32x4 acc2[4][4];
#pragma unroll
        for (int nf = 0; nf < 4; ++nf)
#pragma unroll
            for (int tm = 0; tm < 4; ++tm) acc2[nf][tm] = zero4;
#pragma unroll
        for (int ks = 0; ks < 4; ++ks) {
            bf16x8 a[4], bfr[4];
#pragma unroll
            for (int tm = 0; tm < 4; ++tm) {
                int row = wr * 64 + tm * 16 + l15;
                a[tm] = *(const bf16x8*)((const char*)smem + row * 256 + ((ks * 64 + l4 * 16) ^ ((row & 7) << 4)));
            }
#pragma unroll
            for (int nf = 0; nf < 4; ++nf) {
                int hrow = wc * 64 + nf * 16 + l15;
                bfr[nf] = *(const bf16x8*)((const char*)smem + 32768 + hrow * 256 + ((ks * 64 + l4 * 16) ^ ((hrow & 7) << 4)));
            }
            __builtin_amdgcn_s_setprio(1);
#pragma unroll
            for (int nf = 0; nf < 4; ++nf)
#pragma unroll
                for (int tm = 0; tm < 4; ++tm) acc2[nf][tm] = MFMA16(bfr[nf], a[tm], acc2[nf][tm]);
            __builtin_amdgcn_s_setprio(0);
        }

        f32x4 b14[4];
#pragma unroll
        for (int nf = 0; nf < 4; ++nf)
            b14[nf] = *(const f32x4*)(b1 + hc * 128 + wc * 64 + nf * 16 + l4 * 4);
#pragma unroll
        for (int tm = 0; tm < 4; ++tm) {
            int row = m0 + wr * 64 + tm * 16 + l15;
#pragma unroll
            for (int nf = 0; nf < 4; ++nf) {
                float v0 = gelu(acc2[nf][tm][0] + b14[nf][0]);
                float v1 = gelu(acc2[nf][tm][1] + b14[nf][1]);
                float v2 = gelu(acc2[nf][tm][2] + b14[nf][2]);
                float v3 = gelu(acc2[nf][tm][3] + b14[nf][3]);
                u32x2 pv = { cvtpk(v0, v1), cvtpk(v2, v3) };
                *(u32x2*)(hid + (size_t)row * 512 + hc * 128 + wc * 64 + nf * 16 + l4 * 4) = pv;
            }
        }
        __syncthreads();
    }
}

// ---------- GEMM (round-7): 128x128x512, DB pipeline; MODE 1 = resid+LN, 2 = resid->f32 ----------
template <int MODE>
__global__ __launch_bounds__(256, 2) void gemm4_kernel(const short* __restrict__ A,
                                                       const short* __restrict__ BT,
                                                       const float* __restrict__ bias,
                                                       const float* __restrict__ g,
                                                       const float* __restrict__ bta,
                                                       float* __restrict__ outf,
                                                       short* __restrict__ outb) {
    __shared__ char smem[65536];
    float* red = (float*)smem;

    const int tid = threadIdx.x, wid = tid >> 6, lane = tid & 63;
    const int wr = wid >> 1, wc = wid & 1;
    const int l15 = lane & 15, l4 = lane >> 4;
    const int m0 = blockIdx.x * 128;

    auto stage = [&](int kc, int bi) {
#pragma unroll
        for (int it = 0; it < 4; ++it) {
            int slot = it * 256 + tid;
            int row = slot >> 3, scol = slot & 7;
            int colb = (scol * 16) ^ ((row & 7) << 4);
            gload16((const char*)(A + (size_t)(m0 + row) * 512 + kc * 64) + colb,
                    (char*)smem + bi * 32768 + (it * 256 + wid * 64) * 16);
        }
#pragma unroll
        for (int it = 0; it < 4; ++it) {
            int slot = it * 256 + tid;
            int row = slot >> 3, scol = slot & 7;
            int colb = (scol * 16) ^ ((row & 7) << 4);
            gload16((const char*)(BT + (size_t)row * 512 + kc * 64) + colb,
                    (char*)smem + bi * 32768 + 16384 + (it * 256 + wid * 64) * 16);
        }
    };

    const f32x4 zero4 = {0.f, 0.f, 0.f, 0.f};
    f32x4 acc[4][4];
#pragma unroll
    for (int nf = 0; nf < 4; ++nf)
#pragma unroll
        for (int tm = 0; tm < 4; ++tm) acc[nf][tm] = zero4;

    stage(0, 0);
    __syncthreads();
#pragma unroll
    for (int kc = 0; kc < 8; ++kc) {
        if (kc + 1 < 8) stage(kc + 1, (kc + 1) & 1);
        const char* bufA = (const char*)smem + (kc & 1) * 32768;
        const char* bufB = bufA + 16384;
#pragma unroll
        for (int ks = 0; ks < 2; ++ks) {
            bf16x8 a[4], bfr[4];
#pragma unroll
            for (int tm = 0; tm < 4; ++tm) {
                int row = wr * 64 + tm * 16 + l15;
                a[tm] = *(const bf16x8*)(bufA + row * 128 + ((ks * 64 + l4 * 16) ^ ((row & 7) << 4)));
            }
#pragma unroll
            for (int nf = 0; nf < 4; ++nf) {
                int row = wc * 64 + nf * 16 + l15;
                bfr[nf] = *(const bf16x8*)(bufB + row * 128 + ((ks * 64 + l4 * 16) ^ ((row & 7) << 4)));
            }
            __builtin_amdgcn_s_setprio(1);
#pragma unroll
            for (int nf = 0; nf < 4; ++nf)
#pragma unroll
                for (int tm = 0; tm < 4; ++tm) acc[nf][tm] = MFMA16(bfr[nf], a[tm], acc[nf][tm]);
            __builtin_amdgcn_s_setprio(0);
        }
        __syncthreads();
    }

    f32x4 bv4[4];
#pragma unroll
    for (int nf = 0; nf < 4; ++nf)
        bv4[nf] = *(const f32x4*)(bias + wc * 64 + nf * 16 + l4 * 4);

    float s1[4], s2[4];
#pragma unroll
    for (int tm = 0; tm < 4; ++tm) {
        int row = m0 + wr * 64 + tm * 16 + l15;
        float a1 = 0.f, a2 = 0.f;
#pragma unroll
        for (int nf = 0; nf < 4; ++nf) {
            f32x4 rs = *(const f32x4*)(outf + (size_t)row * 128 + wc * 64 + nf * 16 + l4 * 4);
#pragma unroll
            for (int r = 0; r < 4; ++r) {
                float v = acc[nf][tm][r] + bv4[nf][r] + rs[r];
                acc[nf][tm][r] = v;
                a1 += v; a2 += v * v;
            }
        }
        s1[tm] = a1; s2[tm] = a2;
    }

    if (MODE == 1) {
#pragma unroll
        for (int tm = 0; tm < 4; ++tm) {
            s1[tm] += __shfl_xor(s1[tm], 16); s1[tm] += __shfl_xor(s1[tm], 32);
            s2[tm] += __shfl_xor(s2[tm], 16); s2[tm] += __shfl_xor(s2[tm], 32);
        }
        if (l4 == 0) {
#pragma unroll
            for (int tm = 0; tm < 4; ++tm) {
                int lrow = wr * 64 + tm * 16 + l15;
                red[lrow * 4 + wc * 2] = s1[tm];
                red[lrow * 4 + wc * 2 + 1] = s2[tm];
            }
        }
        __syncthreads();
    }

#pragma unroll
    for (int tm = 0; tm < 4; ++tm) {
        int lrow = wr * 64 + tm * 16 + l15;
        int row = m0 + lrow;
        float mean = 0.f, rstd = 0.f;
        if (MODE == 1) {
            f32x4 rd = *(const f32x4*)(red + lrow * 4);
            float t1 = rd[0] + rd[2], t2 = rd[1] + rd[3];
            mean = t1 * (1.f / 128.f);
            float var = t2 * (1.f / 128.f) - mean * mean;
            rstd = rsqrtf(var + 1e-5f);
        }
#pragma unroll
        for (int nf = 0; nf < 4; ++nf) {
            int col0 = wc * 64 + nf * 16 + l4 * 4;
            *(f32x4*)(outf + (size_t)row * 128 + col0) = acc[nf][tm];
            if (MODE == 1) {
                f32x4 gg = *(const f32x4*)(g + col0);
                f32x4 bb = *(const f32x4*)(bta + col0);
                float w0 = (acc[nf][tm][0] - mean) * rstd * gg[0] + bb[0];
                float w1 = (acc[nf][tm][1] - mean) * rstd * gg[1] + bb[1];
                float w2 = (acc[nf][tm][2] - mean) * rstd * gg[2] + bb[2];
                float w3 = (acc[nf][tm][3] - mean) * rstd * gg[3] + bb[3];
                u32x2 pb = { cvtpk(w0, w1), cvtpk(w2, w3) };
                *(u32x2*)(outb + (size_t)row * 128 + col0) = pb;
            }
        }
    }
}

extern "C" void kernel_launch(void* const* d_in, const int* in_sizes, int n_in,
                              void* d_out, int out_size, void* d_ws, size_t ws_size,
                              hipStream_t stream) {
    const float* x = (const float*)d_in[0];
    const float* w_pe = (const float*)d_in[1];
    const float* b_pe = (const float*)d_in[2];
    const float* P[24];
    for (int i = 0; i < 24; ++i) P[i] = (const float*)d_in[3 + i];
    // per layer s: [s*12+0..11] = ga1, be1, w_qkv, pos, w_o, b_o, ga2, be2, w_m1, b_m1, w_m2, b_m2

    float* out = (float*)d_out;
    const size_t TOK = 100352;

    short* xn = (short*)d_ws;          // TOK*128 bf16
    short* abuf = xn + TOK * 128;      // TOK*512 bf16
    short* wqkv = abuf + TOK * 512;    // 1536x128
    short* wo = wqkv + 196608;         // 128x512
    short* wm1 = wo + 65536;           // 512x128
    short* wm2 = wm1 + 65536;          // 128x512
    short* mtb = wm2 + 65536;          // 4x128x128 bf16
    float* tab = (float*)(mtb + 65536);  // 5*4096 f32
    short* zpad = (short*)(tab + 5 * 4096);  // 256B zeros

    hipMemsetAsync(zpad, 0, 256, stream);
    tabgen_kernel<<<5, 256, 0, stream>>>(P[3], P[15], tab);

    // patch embed + LN1a
    patchln_kernel<<<50176, 256, 0, stream>>>(x, w_pe, b_pe, P[0], P[1], out, xn);

    for (int s = 0; s < 2; ++s) {
        wconv_kernel<<<1536, 256, 0, stream>>>(P[s * 12 + 2], P[s * 12 + 4], P[s * 12 + 8], P[s * 12 + 10],
                                               wqkv, wo, wm1, wm2);
        mtgen_kernel<<<512, 128, 0, stream>>>(P[s * 12 + 2], mtb);

        if (s == 0)
            attn_kernel<0><<<8192, 256, 0, stream>>>(xn, wqkv, mtb, tab, zpad, abuf);
        else
            attn_kernel<1><<<8192, 256, 0, stream>>>(xn, wqkv, mtb, tab, zpad, abuf);

        // proj + residual + LN2 + mlp1 + GELU -> out f32, hidden in abuf
        projmlp_kernel<<<784, 256, 0, stream>>>(
            abuf, wo, wm1, P[s * 12 + 5], P[s * 12 + 6], P[s * 12 + 7], P[s * 12 + 9], out, abuf);

        // mlp2 + residual (+LN1 of next layer for s==0)
        if (s == 0)
            gemm4_kernel<1><<<784, 256, 0, stream>>>(
                abuf, wm2, P[11], P[12], P[13], out, xn);
        else
            gemm4_kernel<2><<<784, 256, 0, stream>>>(
                abuf, wm2, P[23], nullptr, nullptr, out, nullptr);
    }
}